// Round 2
// baseline (337.146 us; speedup 1.0000x reference)
//
#include <hip/hip_runtime.h>
#include <stdint.h>

#define BATCH 8
#define SEQ   2048
#define DIM   512

typedef __attribute__((ext_vector_type(8)))  short short8;    // 8 bf16 (4 VGPRs)
typedef __attribute__((ext_vector_type(16))) float floatx16;  // 32x32 C/D frag

static __device__ __forceinline__ unsigned short f32_bf16(float f) {
  unsigned u = __builtin_bit_cast(unsigned, f);
  u += 0x7FFFu + ((u >> 16) & 1u);          // round-to-nearest-even
  return (unsigned short)(u >> 16);
}
static __device__ __forceinline__ short8 ld_frag8(const unsigned short* p) {
  return __builtin_bit_cast(short8, *reinterpret_cast<const uint4*>(p));
}
static __device__ __forceinline__ void gld_lds16(const unsigned short* g, unsigned short* l) {
  __builtin_amdgcn_global_load_lds((const __attribute__((address_space(1))) unsigned int*)g,
                                   (__attribute__((address_space(3))) unsigned int*)l, 16, 0, 0);
}
static __device__ __forceinline__ float bfu(unsigned short u) {
  return __builtin_bit_cast(float, (unsigned)u << 16);
}

// ---------------- prep: x -> xn (bf16 x-hat, row-major) and xt (bf16 x^T, [b][d][j]) --------
// grid 512 = 8 batches (XCD-pinned &7) x 64 j-tiles of 32 rows ; 256 threads
__global__ __launch_bounds__(256) void prep_kernel(const float* __restrict__ x,
                                                   unsigned short* __restrict__ xn,
                                                   unsigned short* __restrict__ xt) {
  const int b   = blockIdx.x & 7;
  const int jt  = blockIdx.x >> 3;     // 0..63
  const int t   = threadIdx.x;
  const int row = t >> 3;              // 0..31
  const int oct = t & 7;               // 0..7

  __shared__ unsigned short xs[512 * 34];   // [d][j] bf16, pitch 34 u16 (34.8 KB)

  const long rowg = ((long)b * SEQ + jt * 32 + row) * DIM;
  const float* xp = x + rowg;

  float4 v[16];
#pragma unroll
  for (int k = 0; k < 16; ++k)
    v[k] = *reinterpret_cast<const float4*>(xp + k * 32 + oct * 4);

  float acc = 0.f;
#pragma unroll
  for (int k = 0; k < 16; ++k)
    acc += v[k].x*v[k].x + v[k].y*v[k].y + v[k].z*v[k].z + v[k].w*v[k].w;
  acc += __shfl_xor(acc, 1);
  acc += __shfl_xor(acc, 2);
  acc += __shfl_xor(acc, 4);
  const float sc = 1.f / (sqrtf(acc) + 1e-12f);

  // xn straight from registers
  unsigned short* xnp = xn + rowg + oct * 4;
#pragma unroll
  for (int k = 0; k < 16; ++k) {
    ushort4 pk;
    pk.x = f32_bf16(v[k].x * sc); pk.y = f32_bf16(v[k].y * sc);
    pk.z = f32_bf16(v[k].z * sc); pk.w = f32_bf16(v[k].w * sc);
    *reinterpret_cast<ushort4*>(xnp + k * 32) = pk;
  }

  // LDS transpose staging
#pragma unroll
  for (int k = 0; k < 16; ++k) {
    const int d = k * 32 + oct * 4;
    xs[(d + 0) * 34 + row] = f32_bf16(v[k].x);
    xs[(d + 1) * 34 + row] = f32_bf16(v[k].y);
    xs[(d + 2) * 34 + row] = f32_bf16(v[k].z);
    xs[(d + 3) * 34 + row] = f32_bf16(v[k].w);
  }
  __syncthreads();

  // xt: 64B segments per d-row; jt-adjacent blocks (same XCD) complete 128B lines in L2
  unsigned short* xtb = xt + (long)b * DIM * SEQ + jt * 32;
  const int wv = t >> 6, li = t & 63, dsub = li >> 2, jc = li & 3;
#pragma unroll
  for (int it = 0; it < 8; ++it) {
    const int d = it * 64 + wv * 16 + dsub;
    const unsigned* bp = reinterpret_cast<const unsigned*>(&xs[d * 34]);
    uint4 o;
    o.x = bp[jc * 4 + 0]; o.y = bp[jc * 4 + 1];
    o.z = bp[jc * 4 + 2]; o.w = bp[jc * 4 + 3];
    *reinterpret_cast<uint4*>(xtb + (long)d * SEQ + jc * 8) = o;
  }
}

// ---------------- fused flash-style kernel: S -> P=exp(S^2-1) -> O += P.X, l += rowsum(P) ---
// grid 256 = 8 batches (XCD-pinned) x 32 i-tiles of 64 rows
// 1024 threads = 16 waves (4/SIMD, 2x round-1 occupancy); wave (wi,wj) owns [32 i x 64 j/d]
// -> per-wave acc = 32+32 VGPRs, leaving ~60 regs for L2-load pipelining (round-1 had 0).
// LDS: sQ 64KB (xn_i, XOR-swizzled) + sP 64KB (bf16 P, XOR-swizzled) ; B direct from L2
// (read-once per block; per-XCD working set xn_b+xt_b = 4MB = L2 size).
// Row-sums computed IN REGISTERS from the exact bf16 P values (kills round-1's 8-way-conflict
// sP re-reads: 4.45M conflict cycles). 2 barriers per j-tile.
__global__ __launch_bounds__(1024, 4) void fused_kernel(const unsigned short* __restrict__ xn,
                                                        const unsigned short* __restrict__ xt,
                                                        float* __restrict__ out) {
  const int b  = blockIdx.x & 7;
  const int i0 = (blockIdx.x >> 3) * 64;
  const int tid  = threadIdx.x;
  const int w    = tid >> 6;        // 0..15
  const int lane = tid & 63;
  const int ln   = lane & 31;
  const int half = lane >> 5;
  const int wi = w & 1;             // i-half (rows wi*32 .. +31)
  const int wj = w >> 1;            // j-strip (S) / d-strip (PV), 0..7

  __shared__ __align__(16) unsigned short sQ[64 * 512];   // 64 KB
  __shared__ __align__(16) unsigned short sP[64 * 512];   // 64 KB
  __shared__ float sL2[8 * 64];                           // per-wj row-sum partials
  __shared__ float sLi[64];

  const unsigned short* xb  = xn + (size_t)b * SEQ * DIM;
  const unsigned short* xtb = xt + (size_t)b * DIM * SEQ;

  // ---- stage sQ: linear LDS dest + inverse-swizzled global source ----
#pragma unroll
  for (int k = 0; k < 4; ++k) {
    const int u   = tid + k * 1024;
    const int row = u >> 6;                 // uniform per wave per k
    const int c   = u & 63;
    const int sub = (c & 7) ^ ((row ^ (row >> 3)) & 7);
    gld_lds16(xb + (size_t)(i0 + row) * DIM + (c >> 3) * 64 + sub * 8, sQ + u * 8);
  }

  if (tid < 512) sL2[tid] = 0.f;

  floatx16 acc_o[2];
#pragma unroll
  for (int dt = 0; dt < 2; ++dt)
#pragma unroll
    for (int e = 0; e < 16; ++e) acc_o[dt][e] = 0.f;

  // per-lane LDS fragment geometry (A rows for both S and PV: ar = wi*32 + ln)
  const int ar    = wi * 32 + ln;
  const int asw   = (ar ^ (ar >> 3)) & 7;
  const int abase = ar * 512;               // u16 units
  int g[4];
#pragma unroll
  for (int kk = 0; kk < 4; ++kk) g[kk] = ((kk * 2 + half) ^ asw) * 8;

  __syncthreads();                  // sQ staged (vmcnt drained by barrier)

  for (int jt = 0; jt < 4; ++jt) {
    const int j0 = jt * 512;

    // ---------- S phase: per-wave [32 i x 64 j] at j-strip wj*64, K = 512 ----------
    floatx16 acc_s[2];
#pragma unroll
    for (int j2 = 0; j2 < 2; ++j2)
#pragma unroll
      for (int e = 0; e < 16; ++e) acc_s[j2][e] = 0.f;

    const unsigned short* pB0 = xb + (size_t)(j0 + wj * 64 + ln) * DIM + half * 8;
    const unsigned short* pB1 = pB0 + (size_t)32 * DIM;

#pragma unroll
    for (int kc = 0; kc < 8; ++kc) {
#pragma unroll
      for (int kk = 0; kk < 4; ++kk) {
        const short8 aq = ld_frag8(sQ + abase + kc * 64 + g[kk]);
        const short8 b0 = ld_frag8(pB0 + kc * 64 + kk * 16);
        const short8 b1 = ld_frag8(pB1 + kc * 64 + kk * 16);
        acc_s[0] = __builtin_amdgcn_mfma_f32_32x32x16_bf16(aq, b0, acc_s[0], 0, 0, 0);
        acc_s[1] = __builtin_amdgcn_mfma_f32_32x32x16_bf16(aq, b1, acc_s[1], 0, 0, 0);
      }
    }

    // p = exp(s^2-1), rounded to bf16 once; same bits feed sP, PV and the row-sum
    unsigned short us[2][16];
#pragma unroll
    for (int j2 = 0; j2 < 2; ++j2)
#pragma unroll
      for (int r = 0; r < 16; ++r) {
        const float s = acc_s[j2][r];
        us[j2][r] = f32_bf16(__expf(__builtin_fmaf(s, s, -1.0f)));
      }

    // in-register row-sum of the exact bf16 P values (no sP re-read, no bank conflicts)
#pragma unroll
    for (int r = 0; r < 16; ++r) {
      float v = bfu(us[0][r]) + bfu(us[1][r]);
      v += __shfl_xor(v, 1);
      v += __shfl_xor(v, 2);
      v += __shfl_xor(v, 4);
      v += __shfl_xor(v, 8);
      v += __shfl_xor(v, 16);
      if (ln == 0) {
        const int row = wi * 32 + (r & 3) + 8 * (r >> 2) + 4 * half;
        sL2[wj * 64 + row] += v;    // slot private to (wj, row): no race
      }
    }

    __syncthreads();   // all readers of previous sP (PV) are done

    // write bf16 P into swizzled sP
#pragma unroll
    for (int j2 = 0; j2 < 2; ++j2) {
      const int csub = j2 * 4 + (ln >> 3);
      const int coff = ln & 7;
#pragma unroll
      for (int r = 0; r < 16; ++r) {
        const int row = wi * 32 + (r & 3) + 8 * (r >> 2) + 4 * half;
        const int sw  = (row ^ (row >> 3)) & 7;
        sP[row * 512 + wj * 64 + ((csub ^ sw) * 8) + coff] = us[j2][r];
      }
    }

    __syncthreads();   // sP ready

    // ---------- PV phase: per-wave [32 i x 64 d] at d-strip wj*64, K = 512 (this j-tile) --
    const unsigned short* pV0 = xtb + (size_t)(wj * 64 + ln) * SEQ + j0 + half * 8;
    const unsigned short* pV1 = pV0 + (size_t)32 * SEQ;

#pragma unroll
    for (int kc = 0; kc < 8; ++kc) {
#pragma unroll
      for (int kk = 0; kk < 4; ++kk) {
        const short8 ap = ld_frag8(sP + abase + kc * 64 + g[kk]);
        const short8 v0 = ld_frag8(pV0 + kc * 64 + kk * 16);
        const short8 v1 = ld_frag8(pV1 + kc * 64 + kk * 16);
        acc_o[0] = __builtin_amdgcn_mfma_f32_32x32x16_bf16(ap, v0, acc_o[0], 0, 0, 0);
        acc_o[1] = __builtin_amdgcn_mfma_f32_32x32x16_bf16(ap, v1, acc_o[1], 0, 0, 0);
      }
    }
  }

  // final l: all sL2 writes precede each wave's last barrier-A; we've passed barrier-B since
  if (tid < 64) {
    float s = 0.f;
#pragma unroll
    for (int k = 0; k < 8; ++k) s += sL2[k * 64 + tid];
    sLi[tid] = 1.0f / s;
  }
  __syncthreads();

  // epilogue: O / l, coalesced fp32 stores (32 consecutive floats per half-wave)
  float* outb = out + ((size_t)b * SEQ + i0) * DIM + wj * 64;
#pragma unroll
  for (int r = 0; r < 16; ++r) {
    const int row = wi * 32 + (r & 3) + 8 * (r >> 2) + 4 * half;
    const float inv = sLi[row];
#pragma unroll
    for (int dt = 0; dt < 2; ++dt)
      outb[(size_t)row * DIM + dt * 32 + ln] = acc_o[dt][r] * inv;
  }
}

extern "C" void kernel_launch(void* const* d_in, const int* in_sizes, int n_in,
                              void* d_out, int out_size, void* d_ws, size_t ws_size,
                              hipStream_t stream) {
  const float* x = (const float*)d_in[0];
  float* outp = (float*)d_out;

  unsigned short* xn = (unsigned short*)d_ws;                        // 16.78 MB
  unsigned short* xt = xn + (size_t)BATCH * SEQ * DIM;               // 16.78 MB

  prep_kernel <<<BATCH * (SEQ / 32), 256, 0, stream>>>(x, xn, xt);
  fused_kernel<<<BATCH * (SEQ / 64), 1024, 0, stream>>>(xn, xt, outp);
}

// Round 3
// 168.380 us; speedup vs baseline: 2.0023x; 2.0023x over previous
//
#include <hip/hip_runtime.h>
#include <stdint.h>

#define BATCH 8
#define SEQ   2048
#define DIM   512

typedef __attribute__((ext_vector_type(8)))  short short8;    // 8 bf16 (4 VGPRs)
typedef __attribute__((ext_vector_type(16))) float floatx16;  // 32x32 C/D frag

static __device__ __forceinline__ unsigned short f32_bf16(float f) {
  unsigned u = __builtin_bit_cast(unsigned, f);
  u += 0x7FFFu + ((u >> 16) & 1u);          // round-to-nearest-even
  return (unsigned short)(u >> 16);
}
static __device__ __forceinline__ short8 ld_frag8(const unsigned short* p) {
  return __builtin_bit_cast(short8, *reinterpret_cast<const uint4*>(p));
}
static __device__ __forceinline__ void gld_lds16(const unsigned short* g, unsigned short* l) {
  __builtin_amdgcn_global_load_lds((const __attribute__((address_space(1))) unsigned int*)g,
                                   (__attribute__((address_space(3))) unsigned int*)l, 16, 0, 0);
}
static __device__ __forceinline__ float bf_lo(unsigned u) {
  return __builtin_bit_cast(float, u << 16);
}
static __device__ __forceinline__ float bf_hi(unsigned u) {
  return __builtin_bit_cast(float, u & 0xFFFF0000u);
}
static __device__ __forceinline__ float bfu(unsigned short u) {
  return __builtin_bit_cast(float, (unsigned)u << 16);
}

// ---------------- prep: x -> xn (bf16 x-hat, row-major) and xt (bf16 x^T, [b][d][j]) --------
// grid 512 = 8 batches (XCD-pinned &7) x 64 j-tiles of 32 rows ; 256 threads
__global__ __launch_bounds__(256) void prep_kernel(const float* __restrict__ x,
                                                   unsigned short* __restrict__ xn,
                                                   unsigned short* __restrict__ xt) {
  const int b   = blockIdx.x & 7;
  const int jt  = blockIdx.x >> 3;     // 0..63
  const int t   = threadIdx.x;
  const int row = t >> 3;              // 0..31
  const int oct = t & 7;               // 0..7

  __shared__ unsigned short xs[512 * 34];   // [d][j] bf16, pitch 34 u16 (34.8 KB)

  const long rowg = ((long)b * SEQ + jt * 32 + row) * DIM;
  const float* xp = x + rowg;

  float4 v[16];
#pragma unroll
  for (int k = 0; k < 16; ++k)
    v[k] = *reinterpret_cast<const float4*>(xp + k * 32 + oct * 4);

  float acc = 0.f;
#pragma unroll
  for (int k = 0; k < 16; ++k)
    acc += v[k].x*v[k].x + v[k].y*v[k].y + v[k].z*v[k].z + v[k].w*v[k].w;
  acc += __shfl_xor(acc, 1);
  acc += __shfl_xor(acc, 2);
  acc += __shfl_xor(acc, 4);
  const float sc = 1.f / (sqrtf(acc) + 1e-12f);

  // xn straight from registers
  unsigned short* xnp = xn + rowg + oct * 4;
#pragma unroll
  for (int k = 0; k < 16; ++k) {
    ushort4 pk;
    pk.x = f32_bf16(v[k].x * sc); pk.y = f32_bf16(v[k].y * sc);
    pk.z = f32_bf16(v[k].z * sc); pk.w = f32_bf16(v[k].w * sc);
    *reinterpret_cast<ushort4*>(xnp + k * 32) = pk;
  }

  // LDS transpose staging: scalar u16 writes, bank = 4*oct + row/2 + const -> free
#pragma unroll
  for (int k = 0; k < 16; ++k) {
    const int d = k * 32 + oct * 4;
    xs[(d + 0) * 34 + row] = f32_bf16(v[k].x);
    xs[(d + 1) * 34 + row] = f32_bf16(v[k].y);
    xs[(d + 2) * 34 + row] = f32_bf16(v[k].z);
    xs[(d + 3) * 34 + row] = f32_bf16(v[k].w);
  }
  __syncthreads();

  // xt: 64B segments per d-row; jt-adjacent blocks (same XCD) complete 128B lines in L2
  unsigned short* xtb = xt + (long)b * DIM * SEQ + jt * 32;
  const int wv = t >> 6, li = t & 63, dsub = li >> 2, jc = li & 3;
#pragma unroll
  for (int it = 0; it < 8; ++it) {
    const int d = it * 64 + wv * 16 + dsub;
    const unsigned* bp = reinterpret_cast<const unsigned*>(&xs[d * 34]);
    uint4 o;
    o.x = bp[jc * 4 + 0]; o.y = bp[jc * 4 + 1];
    o.z = bp[jc * 4 + 2]; o.w = bp[jc * 4 + 3];
    *reinterpret_cast<uint4*>(xtb + (long)d * SEQ + jc * 8) = o;
  }
}

// ---------------- gemm1 (symmetric): P[b,i,j] = bf16(exp(S^2-1)), S = xn.xn^T ----------
// P is symmetric bit-exactly (MFMA dot order depends only on k) -> compute only upper-
// triangle tiles: grid 8 x 136. Off-diagonal blocks also store the transposed tile
// directly from registers (4-row ushort4 packs; lane-halves give 16B-contiguous chunks,
// L2 write-combines to full lines) and add column-sums (= mirror row-sums) to lw.
// MFMA work + staging fetch halve; write bytes unchanged; LDS stays 34.8KB (4 blk/CU).
__global__ __launch_bounds__(256, 4) void gemm1_kernel(const unsigned short* __restrict__ xn,
                                                       unsigned short* __restrict__ P,
                                                       float* __restrict__ lw) {
  const int b   = blockIdx.x & 7;
  int idx = blockIdx.x >> 3;           // 0..135 -> (ti, tj), ti <= tj
  int ti = 0;
#pragma unroll 1
  while (idx >= 16 - ti) { idx -= 16 - ti; ++ti; }
  const int tj = ti + idx;
  const int i0 = ti * 128;
  const int j0 = tj * 128;

  const int tid  = threadIdx.x;
  const int w    = tid >> 6;
  const int lane = tid & 63;
  const int ln   = lane & 31;
  const int half = lane >> 5;

  __shared__ __align__(16) unsigned short smem[17408];   // staging 32KB ; epilogue sP 128x136
  unsigned short* sA = smem;
  unsigned short* sB = smem + 8192;

  const unsigned short* xb = xn + (long)b * SEQ * DIM;
  const unsigned short* Ag = xb + (long)i0 * DIM;
  const unsigned short* Bg = xb + (long)j0 * DIM;

  floatx16 acc[2][2];
#pragma unroll
  for (int mt = 0; mt < 2; ++mt)
#pragma unroll
    for (int nt = 0; nt < 2; ++nt)
#pragma unroll
      for (int i = 0; i < 16; ++i) acc[mt][nt][i] = 0.f;

  const int r0 = (w >> 1) * 64;
  const int c0 = (w & 1) * 64;

  for (int kc = 0; kc < 8; ++kc) {
#pragma unroll
    for (int k = 0; k < 4; ++k) {
      int u = tid + k * 256;
      int row = u >> 3, c = u & 7;
      int gc = (c ^ ((row ^ (row >> 3)) & 7)) * 8;   // conflict-free swizzle key
      gld_lds16(Ag + (long)row * DIM + kc * 64 + gc, sA + u * 8);
      gld_lds16(Bg + (long)row * DIM + kc * 64 + gc, sB + u * 8);
    }
    __syncthreads();
#pragma unroll
    for (int kk = 0; kk < 4; ++kk) {
      const int cc = kk * 2 + half;
      short8 af[2], bf[2];
#pragma unroll
      for (int mt = 0; mt < 2; ++mt) {
        int r = r0 + mt * 32 + ln;
        af[mt] = ld_frag8(sA + r * 64 + ((cc ^ ((r ^ (r >> 3)) & 7)) * 8));
      }
#pragma unroll
      for (int nt = 0; nt < 2; ++nt) {
        int r = c0 + nt * 32 + ln;
        bf[nt] = ld_frag8(sB + r * 64 + ((cc ^ ((r ^ (r >> 3)) & 7)) * 8));
      }
#pragma unroll
      for (int mt = 0; mt < 2; ++mt)
#pragma unroll
        for (int nt = 0; nt < 2; ++nt)
          acc[mt][nt] = __builtin_amdgcn_mfma_f32_32x32x16_bf16(af[mt], bf[nt], acc[mt][nt], 0, 0, 0);
    }
    __syncthreads();
  }

  // epilogue: p = bf16(exp(s^2-1)) once into registers; feed sP, transposed stores, sums
  unsigned short pb[2][2][16];
  unsigned short* sP = smem;
#pragma unroll
  for (int mt = 0; mt < 2; ++mt)
#pragma unroll
    for (int nt = 0; nt < 2; ++nt) {
      const int col = c0 + nt * 32 + ln;
#pragma unroll
      for (int r = 0; r < 16; ++r) {
        float s = acc[mt][nt][r];
        unsigned short pv = f32_bf16(__expf(__builtin_fmaf(s, s, -1.0f)));
        pb[mt][nt][r] = pv;
        int row = r0 + mt * 32 + (r & 3) + 8 * (r >> 2) + 4 * half;
        sP[row * 136 + col] = pv;
      }
    }
  __syncthreads();

  unsigned short* Pg = P + (long)b * SEQ * SEQ;
  float* lwi = lw + b * SEQ + i0;
  float* lwj = lw + b * SEQ + j0;

  // tile (ti,tj): coalesced stores + fused row-sums (identical to round-0 path)
#pragma unroll
  for (int k = 0; k < 8; ++k) {
    int u = tid + k * 256;
    int row = u >> 4, c16 = u & 15;
    uint4 o = *reinterpret_cast<const uint4*>(sP + row * 136 + c16 * 8);
    *reinterpret_cast<uint4*>(Pg + (long)(i0 + row) * SEQ + j0 + c16 * 8) = o;
    float s = bf_lo(o.x) + bf_hi(o.x) + bf_lo(o.y) + bf_hi(o.y)
            + bf_lo(o.z) + bf_hi(o.z) + bf_lo(o.w) + bf_hi(o.w);
    s += __shfl_xor(s, 1);
    s += __shfl_xor(s, 2);
    s += __shfl_xor(s, 4);
    s += __shfl_xor(s, 8);
    if ((tid & 15) == 0) atomicAdd(&lwi[row], s);
  }

  if (ti != tj) {
    // column sums (= row sums of the mirror tile) from the exact bf16 register values
#pragma unroll
    for (int nt = 0; nt < 2; ++nt) {
      const int c = c0 + nt * 32 + ln;
      float s = 0.f;
#pragma unroll
      for (int mt = 0; mt < 2; ++mt)
#pragma unroll
        for (int r = 0; r < 16; ++r) s += bfu(pb[mt][nt][r]);
      s += __shfl_xor(s, 32);           // combine the two row-halves of this wave
      if (half == 0) atomicAdd(&lwj[c], s);
    }
    // transposed tile (tj,ti): regs 4q..4q+3 are 4 consecutive rows -> ushort4 packs;
    // lanes (ln, ln+32) write adjacent 8B -> 16B contiguous per store instruction
#pragma unroll
    for (int nt = 0; nt < 2; ++nt) {
      const int c = c0 + nt * 32 + ln;
      unsigned short* dst = Pg + (long)(j0 + c) * SEQ + i0 + r0 + half * 4;
#pragma unroll
      for (int mt = 0; mt < 2; ++mt)
#pragma unroll
        for (int rq = 0; rq < 4; ++rq) {
          ushort4 pk;
          pk.x = pb[mt][nt][rq * 4 + 0];
          pk.y = pb[mt][nt][rq * 4 + 1];
          pk.z = pb[mt][nt][rq * 4 + 2];
          pk.w = pb[mt][nt][rq * 4 + 3];
          *reinterpret_cast<ushort4*>(dst + mt * 32 + rq * 8) = pk;
        }
    }
  }
}

// ---------------- gemm2: out[b,i,d] = (P . x) / l ----------------
// grid 512 = 8 batches x 16 i-tiles x 4 d-tiles ; 256 threads = 4 waves
// d-FAST block ordering: consecutive same-XCD blocks share i0 -> the 512KB of P rows
// is fetched from HBM once and reused 3x from L2 (was 16 blocks apart = evicted).
__global__ __launch_bounds__(256, 3) void gemm2_kernel(const unsigned short* __restrict__ P,
                                                       const unsigned short* __restrict__ xt,
                                                       const float* __restrict__ lw,
                                                       float* __restrict__ out) {
  const int b  = blockIdx.x & 7;
  const int t  = blockIdx.x >> 3;
  const int i0 = (t >> 2) * 128;       // d-fast: i0 slow
  const int n0 = (t & 3) * 128;        // d-fast: n0 fast
  const int tid  = threadIdx.x;
  const int w    = tid >> 6;
  const int lane = tid & 63;
  const int ln   = lane & 31;
  const int half = lane >> 5;

  __shared__ __align__(16) unsigned short sA[8192];
  __shared__ __align__(16) unsigned short sB[8192];
  __shared__ float sl[128];

  const unsigned short* Ag = P  + (long)b * SEQ * SEQ + (long)i0 * SEQ;
  const unsigned short* Bg = xt + (long)b * DIM * SEQ + (long)n0 * SEQ;

  if (tid < 128) sl[tid] = lw[b * SEQ + i0 + tid];

  floatx16 acc[2][2];
#pragma unroll
  for (int mt = 0; mt < 2; ++mt)
#pragma unroll
    for (int nt = 0; nt < 2; ++nt)
#pragma unroll
      for (int i = 0; i < 16; ++i) acc[mt][nt][i] = 0.f;

  const int r0 = (w >> 1) * 64;
  const int c0 = (w & 1) * 64;

  for (int kc = 0; kc < 32; ++kc) {
#pragma unroll
    for (int k = 0; k < 4; ++k) {
      int u = tid + k * 256;
      int row = u >> 3, c = u & 7;
      int gc = (c ^ ((row ^ (row >> 3)) & 7)) * 8;   // conflict-free swizzle key
      gld_lds16(Ag + (long)row * SEQ + kc * 64 + gc, sA + u * 8);
      gld_lds16(Bg + (long)row * SEQ + kc * 64 + gc, sB + u * 8);
    }
    __syncthreads();
#pragma unroll
    for (int kk = 0; kk < 4; ++kk) {
      const int cc = kk * 2 + half;
      short8 af[2], bf[2];
#pragma unroll
      for (int mt = 0; mt < 2; ++mt) {
        int r = r0 + mt * 32 + ln;
        af[mt] = ld_frag8(sA + r * 64 + ((cc ^ ((r ^ (r >> 3)) & 7)) * 8));
      }
#pragma unroll
      for (int nt = 0; nt < 2; ++nt) {
        int r = c0 + nt * 32 + ln;
        bf[nt] = ld_frag8(sB + r * 64 + ((cc ^ ((r ^ (r >> 3)) & 7)) * 8));
      }
#pragma unroll
      for (int mt = 0; mt < 2; ++mt)
#pragma unroll
        for (int nt = 0; nt < 2; ++nt)
          acc[mt][nt] = __builtin_amdgcn_mfma_f32_32x32x16_bf16(af[mt], bf[nt], acc[mt][nt], 0, 0, 0);
    }
    __syncthreads();
  }

  // epilogue: divide by l, coalesced fp32 stores
  float* outb = out + (long)b * SEQ * DIM;
#pragma unroll
  for (int mt = 0; mt < 2; ++mt)
#pragma unroll
    for (int r = 0; r < 16; ++r) {
      const int row = r0 + mt * 32 + (r & 3) + 8 * (r >> 2) + 4 * half;
      const float inv = 1.0f / sl[row];
#pragma unroll
      for (int nt = 0; nt < 2; ++nt) {
        const int col = c0 + nt * 32 + ln;
        outb[(long)(i0 + row) * DIM + n0 + col] = acc[mt][nt][r] * inv;
      }
    }
}

extern "C" void kernel_launch(void* const* d_in, const int* in_sizes, int n_in,
                              void* d_out, int out_size, void* d_ws, size_t ws_size,
                              hipStream_t stream) {
  const float* x = (const float*)d_in[0];
  float* outp = (float*)d_out;

  unsigned short* xn = (unsigned short*)d_ws;                        // 16.78 MB
  unsigned short* xt = xn + (size_t)BATCH * SEQ * DIM;               // 16.78 MB
  unsigned short* Pw = xt + (size_t)BATCH * SEQ * DIM;               // 67.1 MB
  float*          lw = (float*)(Pw + (size_t)BATCH * SEQ * SEQ);     // 64 KB

  hipMemsetAsync(lw, 0, (size_t)BATCH * SEQ * sizeof(float), stream);
  prep_kernel <<<BATCH * (SEQ / 32),  256, 0, stream>>>(x, xn, xt);
  gemm1_kernel<<<BATCH * 136,         256, 0, stream>>>(xn, Pw, lw);
  gemm2_kernel<<<BATCH * 16 * 4,      256, 0, stream>>>(Pw, xt, lw, outp);
}

// Round 4
// 166.396 us; speedup vs baseline: 2.0262x; 1.0119x over previous
//
#include <hip/hip_runtime.h>
#include <stdint.h>

#define BATCH 8
#define SEQ   2048
#define DIM   512

typedef __attribute__((ext_vector_type(8)))  short short8;    // 8 bf16 (4 VGPRs)
typedef __attribute__((ext_vector_type(16))) float floatx16;  // 32x32 C/D frag

static __device__ __forceinline__ unsigned short f32_bf16(float f) {
  unsigned u = __builtin_bit_cast(unsigned, f);
  u += 0x7FFFu + ((u >> 16) & 1u);          // round-to-nearest-even
  return (unsigned short)(u >> 16);
}
static __device__ __forceinline__ short8 ld_frag8(const unsigned short* p) {
  return __builtin_bit_cast(short8, *reinterpret_cast<const uint4*>(p));
}
static __device__ __forceinline__ void gld_lds16(const unsigned short* g, unsigned short* l) {
  __builtin_amdgcn_global_load_lds((const __attribute__((address_space(1))) unsigned int*)g,
                                   (__attribute__((address_space(3))) unsigned int*)l, 16, 0, 0);
}
static __device__ __forceinline__ float bf_lo(unsigned u) {
  return __builtin_bit_cast(float, u << 16);
}
static __device__ __forceinline__ float bf_hi(unsigned u) {
  return __builtin_bit_cast(float, u & 0xFFFF0000u);
}
static __device__ __forceinline__ float bfu(unsigned short u) {
  return __builtin_bit_cast(float, (unsigned)u << 16);
}

// ---------------- prep: x -> xn (bf16 x-hat, row-major) and xt (bf16 x^T, BLOCKED) ---------
// xt layout: [b][jt][d][j&31]  (jt = j>>5) -> each block owns ONE contiguous 32KB chunk.
// Store phase: per-wave instruction covers a contiguous (lane-permuted) 4KB region ->
// fully coalesced 128B lines (was: 16 scattered 64B segments/inst at 4KB stride).
// grid 512 = 8 batches (XCD-pinned &7) x 64 j-tiles of 32 rows ; 256 threads
__global__ __launch_bounds__(256) void prep_kernel(const float* __restrict__ x,
                                                   unsigned short* __restrict__ xn,
                                                   unsigned short* __restrict__ xt) {
  const int b   = blockIdx.x & 7;
  const int jt  = blockIdx.x >> 3;     // 0..63
  const int t   = threadIdx.x;
  const int row = t >> 3;              // 0..31
  const int oct = t & 7;               // 0..7

  __shared__ unsigned short xs[512 * 34];   // [d][j] bf16, pitch 34 u16 (34.8 KB)

  const long rowg = ((long)b * SEQ + jt * 32 + row) * DIM;
  const float* xp = x + rowg;

  float4 v[16];
#pragma unroll
  for (int k = 0; k < 16; ++k)
    v[k] = *reinterpret_cast<const float4*>(xp + k * 32 + oct * 4);

  float acc = 0.f;
#pragma unroll
  for (int k = 0; k < 16; ++k)
    acc += v[k].x*v[k].x + v[k].y*v[k].y + v[k].z*v[k].z + v[k].w*v[k].w;
  acc += __shfl_xor(acc, 1);
  acc += __shfl_xor(acc, 2);
  acc += __shfl_xor(acc, 4);
  const float sc = 1.f / (sqrtf(acc) + 1e-12f);

  // xn straight from registers
  unsigned short* xnp = xn + rowg + oct * 4;
#pragma unroll
  for (int k = 0; k < 16; ++k) {
    ushort4 pk;
    pk.x = f32_bf16(v[k].x * sc); pk.y = f32_bf16(v[k].y * sc);
    pk.z = f32_bf16(v[k].z * sc); pk.w = f32_bf16(v[k].w * sc);
    *reinterpret_cast<ushort4*>(xnp + k * 32) = pk;
  }

  // LDS transpose staging: scalar u16 writes, bank = 4*oct + row/2 + const -> free
#pragma unroll
  for (int k = 0; k < 16; ++k) {
    const int d = k * 32 + oct * 4;
    xs[(d + 0) * 34 + row] = f32_bf16(v[k].x);
    xs[(d + 1) * 34 + row] = f32_bf16(v[k].y);
    xs[(d + 2) * 34 + row] = f32_bf16(v[k].z);
    xs[(d + 3) * 34 + row] = f32_bf16(v[k].w);
  }
  __syncthreads();

  // xt chunk store: contiguous 32KB, fully coalesced.
  // q = (t&3)^((t>>4)&3): bijective per 16-thread group -> coverage + coalescing intact,
  // spreads the pitch-34 LDS column reads across banks (4-way -> ~2-way).
  unsigned short* xtb = xt + (size_t)(b * 64 + jt) * (512 * 32);
#pragma unroll
  for (int it = 0; it < 8; ++it) {
    const int a = t >> 2;                      // 0..63 d-sub
    const int q = (t & 3) ^ ((t >> 4) & 3);    // read/store group 0..3
    const int d = it * 64 + a;
    const unsigned* bp = reinterpret_cast<const unsigned*>(&xs[d * 34 + q * 8]);
    uint4 o;
    o.x = bp[0]; o.y = bp[1]; o.z = bp[2]; o.w = bp[3];
    *reinterpret_cast<uint4*>(xtb + d * 32 + q * 8) = o;
  }
}

// ---------------- gemm1 (symmetric): P[b,i,j] = bf16(exp(S^2-1)), S = xn.xn^T ----------
// P is symmetric bit-exactly (MFMA dot order depends only on k) -> compute only upper-
// triangle tiles: grid 8 x 136. Off-diagonal blocks also store the transposed tile
// directly from registers and add column-sums (= mirror row-sums) to lw.
__global__ __launch_bounds__(256, 4) void gemm1_kernel(const unsigned short* __restrict__ xn,
                                                       unsigned short* __restrict__ P,
                                                       float* __restrict__ lw) {
  const int b   = blockIdx.x & 7;
  int idx = blockIdx.x >> 3;           // 0..135 -> (ti, tj), ti <= tj
  int ti = 0;
#pragma unroll 1
  while (idx >= 16 - ti) { idx -= 16 - ti; ++ti; }
  const int tj = ti + idx;
  const int i0 = ti * 128;
  const int j0 = tj * 128;

  const int tid  = threadIdx.x;
  const int w    = tid >> 6;
  const int lane = tid & 63;
  const int ln   = lane & 31;
  const int half = lane >> 5;

  __shared__ __align__(16) unsigned short smem[17408];   // staging 32KB ; epilogue sP 128x136
  unsigned short* sA = smem;
  unsigned short* sB = smem + 8192;

  const unsigned short* xb = xn + (long)b * SEQ * DIM;
  const unsigned short* Ag = xb + (long)i0 * DIM;
  const unsigned short* Bg = xb + (long)j0 * DIM;

  floatx16 acc[2][2];
#pragma unroll
  for (int mt = 0; mt < 2; ++mt)
#pragma unroll
    for (int nt = 0; nt < 2; ++nt)
#pragma unroll
      for (int i = 0; i < 16; ++i) acc[mt][nt][i] = 0.f;

  const int r0 = (w >> 1) * 64;
  const int c0 = (w & 1) * 64;

  for (int kc = 0; kc < 8; ++kc) {
#pragma unroll
    for (int k = 0; k < 4; ++k) {
      int u = tid + k * 256;
      int row = u >> 3, c = u & 7;
      int gc = (c ^ ((row ^ (row >> 3)) & 7)) * 8;   // conflict-free swizzle key
      gld_lds16(Ag + (long)row * DIM + kc * 64 + gc, sA + u * 8);
      gld_lds16(Bg + (long)row * DIM + kc * 64 + gc, sB + u * 8);
    }
    __syncthreads();
#pragma unroll
    for (int kk = 0; kk < 4; ++kk) {
      const int cc = kk * 2 + half;
      short8 af[2], bf[2];
#pragma unroll
      for (int mt = 0; mt < 2; ++mt) {
        int r = r0 + mt * 32 + ln;
        af[mt] = ld_frag8(sA + r * 64 + ((cc ^ ((r ^ (r >> 3)) & 7)) * 8));
      }
#pragma unroll
      for (int nt = 0; nt < 2; ++nt) {
        int r = c0 + nt * 32 + ln;
        bf[nt] = ld_frag8(sB + r * 64 + ((cc ^ ((r ^ (r >> 3)) & 7)) * 8));
      }
#pragma unroll
      for (int mt = 0; mt < 2; ++mt)
#pragma unroll
        for (int nt = 0; nt < 2; ++nt)
          acc[mt][nt] = __builtin_amdgcn_mfma_f32_32x32x16_bf16(af[mt], bf[nt], acc[mt][nt], 0, 0, 0);
    }
    __syncthreads();
  }

  // epilogue: p = bf16(exp(s^2-1)) once into registers; feed sP, transposed stores, sums
  unsigned short pb[2][2][16];
  unsigned short* sP = smem;
#pragma unroll
  for (int mt = 0; mt < 2; ++mt)
#pragma unroll
    for (int nt = 0; nt < 2; ++nt) {
      const int col = c0 + nt * 32 + ln;
#pragma unroll
      for (int r = 0; r < 16; ++r) {
        float s = acc[mt][nt][r];
        unsigned short pv = f32_bf16(__expf(__builtin_fmaf(s, s, -1.0f)));
        pb[mt][nt][r] = pv;
        int row = r0 + mt * 32 + (r & 3) + 8 * (r >> 2) + 4 * half;
        sP[row * 136 + col] = pv;
      }
    }
  __syncthreads();

  unsigned short* Pg = P + (long)b * SEQ * SEQ;
  float* lwi = lw + b * SEQ + i0;
  float* lwj = lw + b * SEQ + j0;

  // tile (ti,tj): coalesced stores + fused row-sums
#pragma unroll
  for (int k = 0; k < 8; ++k) {
    int u = tid + k * 256;
    int row = u >> 4, c16 = u & 15;
    uint4 o = *reinterpret_cast<const uint4*>(sP + row * 136 + c16 * 8);
    *reinterpret_cast<uint4*>(Pg + (long)(i0 + row) * SEQ + j0 + c16 * 8) = o;
    float s = bf_lo(o.x) + bf_hi(o.x) + bf_lo(o.y) + bf_hi(o.y)
            + bf_lo(o.z) + bf_hi(o.z) + bf_lo(o.w) + bf_hi(o.w);
    s += __shfl_xor(s, 1);
    s += __shfl_xor(s, 2);
    s += __shfl_xor(s, 4);
    s += __shfl_xor(s, 8);
    if ((tid & 15) == 0) atomicAdd(&lwi[row], s);
  }

  if (ti != tj) {
    // column sums (= row sums of the mirror tile) from the exact bf16 register values
#pragma unroll
    for (int nt = 0; nt < 2; ++nt) {
      const int c = c0 + nt * 32 + ln;
      float s = 0.f;
#pragma unroll
      for (int mt = 0; mt < 2; ++mt)
#pragma unroll
        for (int r = 0; r < 16; ++r) s += bfu(pb[mt][nt][r]);
      s += __shfl_xor(s, 32);           // combine the two row-halves of this wave
      if (half == 0) atomicAdd(&lwj[c], s);
    }
    // transposed tile (tj,ti): regs 4q..4q+3 are 4 consecutive rows -> ushort4 packs;
    // lanes (ln, ln+32) write adjacent 8B -> 16B contiguous per store instruction
#pragma unroll
    for (int nt = 0; nt < 2; ++nt) {
      const int c = c0 + nt * 32 + ln;
      unsigned short* dst = Pg + (long)(j0 + c) * SEQ + i0 + r0 + half * 4;
#pragma unroll
      for (int mt = 0; mt < 2; ++mt)
#pragma unroll
        for (int rq = 0; rq < 4; ++rq) {
          ushort4 pk;
          pk.x = pb[mt][nt][rq * 4 + 0];
          pk.y = pb[mt][nt][rq * 4 + 1];
          pk.z = pb[mt][nt][rq * 4 + 2];
          pk.w = pb[mt][nt][rq * 4 + 3];
          *reinterpret_cast<ushort4*>(dst + mt * 32 + rq * 8) = pk;
        }
    }
  }
}

// ---------------- gemm2: out[b,i,d] = (P . x) / l ----------------
// grid 512 = 8 batches x 16 i-tiles x 4 d-tiles ; 256 threads = 4 waves ; d-FAST ordering
// B staging reads the BLOCKED xt layout: j = kc*64 + sub*8 lives in chunk kc*2+(sub>>2)
// at row (n0+row), offset (sub&3)*8. Same bytes -> same sB slots as the flat layout.
__global__ __launch_bounds__(256, 3) void gemm2_kernel(const unsigned short* __restrict__ P,
                                                       const unsigned short* __restrict__ xt,
                                                       const float* __restrict__ lw,
                                                       float* __restrict__ out) {
  const int b  = blockIdx.x & 7;
  const int t  = blockIdx.x >> 3;
  const int i0 = (t >> 2) * 128;       // d-fast: i0 slow
  const int n0 = (t & 3) * 128;        // d-fast: n0 fast
  const int tid  = threadIdx.x;
  const int w    = tid >> 6;
  const int lane = tid & 63;
  const int ln   = lane & 31;
  const int half = lane >> 5;

  __shared__ __align__(16) unsigned short sA[8192];
  __shared__ __align__(16) unsigned short sB[8192];
  __shared__ float sl[128];

  const unsigned short* Ag = P  + (long)b * SEQ * SEQ + (long)i0 * SEQ;
  const unsigned short* Bg = xt + (size_t)b * DIM * SEQ;   // blocked chunks base

  if (tid < 128) sl[tid] = lw[b * SEQ + i0 + tid];

  floatx16 acc[2][2];
#pragma unroll
  for (int mt = 0; mt < 2; ++mt)
#pragma unroll
    for (int nt = 0; nt < 2; ++nt)
#pragma unroll
      for (int i = 0; i < 16; ++i) acc[mt][nt][i] = 0.f;

  const int r0 = (w >> 1) * 64;
  const int c0 = (w & 1) * 64;

  for (int kc = 0; kc < 32; ++kc) {
#pragma unroll
    for (int k = 0; k < 4; ++k) {
      int u = tid + k * 256;
      int row = u >> 3, c = u & 7;
      int sub = c ^ ((row ^ (row >> 3)) & 7);        // conflict-free swizzle key
      gld_lds16(Ag + (long)row * SEQ + kc * 64 + sub * 8, sA + u * 8);
      gld_lds16(Bg + ((size_t)(kc * 2 + (sub >> 2)) * 512 + (n0 + row)) * 32 + (sub & 3) * 8,
                sB + u * 8);
    }
    __syncthreads();
#pragma unroll
    for (int kk = 0; kk < 4; ++kk) {
      const int cc = kk * 2 + half;
      short8 af[2], bf[2];
#pragma unroll
      for (int mt = 0; mt < 2; ++mt) {
        int r = r0 + mt * 32 + ln;
        af[mt] = ld_frag8(sA + r * 64 + ((cc ^ ((r ^ (r >> 3)) & 7)) * 8));
      }
#pragma unroll
      for (int nt = 0; nt < 2; ++nt) {
        int r = c0 + nt * 32 + ln;
        bf[nt] = ld_frag8(sB + r * 64 + ((cc ^ ((r ^ (r >> 3)) & 7)) * 8));
      }
#pragma unroll
      for (int mt = 0; mt < 2; ++mt)
#pragma unroll
        for (int nt = 0; nt < 2; ++nt)
          acc[mt][nt] = __builtin_amdgcn_mfma_f32_32x32x16_bf16(af[mt], bf[nt], acc[mt][nt], 0, 0, 0);
    }
    __syncthreads();
  }

  // epilogue: divide by l, coalesced fp32 stores
  float* outb = out + (long)b * SEQ * DIM;
#pragma unroll
  for (int mt = 0; mt < 2; ++mt)
#pragma unroll
    for (int r = 0; r < 16; ++r) {
      const int row = r0 + mt * 32 + (r & 3) + 8 * (r >> 2) + 4 * half;
      const float inv = 1.0f / sl[row];
#pragma unroll
      for (int nt = 0; nt < 2; ++nt) {
        const int col = c0 + nt * 32 + ln;
        outb[(long)(i0 + row) * DIM + n0 + col] = acc[mt][nt][r] * inv;
      }
    }
}

extern "C" void kernel_launch(void* const* d_in, const int* in_sizes, int n_in,
                              void* d_out, int out_size, void* d_ws, size_t ws_size,
                              hipStream_t stream) {
  const float* x = (const float*)d_in[0];
  float* outp = (float*)d_out;

  unsigned short* xn = (unsigned short*)d_ws;                        // 16.78 MB
  unsigned short* xt = xn + (size_t)BATCH * SEQ * DIM;               // 16.78 MB (blocked)
  unsigned short* Pw = xt + (size_t)BATCH * SEQ * DIM;               // 67.1 MB
  float*          lw = (float*)(Pw + (size_t)BATCH * SEQ * SEQ);     // 64 KB

  hipMemsetAsync(lw, 0, (size_t)BATCH * SEQ * sizeof(float), stream);
  prep_kernel <<<BATCH * (SEQ / 32),  256, 0, stream>>>(x, xn, xt);
  gemm1_kernel<<<BATCH * 136,         256, 0, stream>>>(xn, Pw, lw);
  gemm2_kernel<<<BATCH * 16 * 4,      256, 0, stream>>>(Pw, xt, lw, outp);
}

// Round 5
// 163.261 us; speedup vs baseline: 2.0651x; 1.0192x over previous
//
#include <hip/hip_runtime.h>
#include <stdint.h>

#define BATCH 8
#define SEQ   2048
#define DIM   512

typedef __attribute__((ext_vector_type(8)))  short short8;    // 8 bf16 (4 VGPRs)
typedef __attribute__((ext_vector_type(16))) float floatx16;  // 32x32 C/D frag

static __device__ __forceinline__ unsigned short f32_bf16(float f) {
  unsigned u = __builtin_bit_cast(unsigned, f);
  u += 0x7FFFu + ((u >> 16) & 1u);          // round-to-nearest-even
  return (unsigned short)(u >> 16);
}
static __device__ __forceinline__ short8 ld_frag8(const unsigned short* p) {
  return __builtin_bit_cast(short8, *reinterpret_cast<const uint4*>(p));
}
static __device__ __forceinline__ void gld_lds16(const unsigned short* g, unsigned short* l) {
  __builtin_amdgcn_global_load_lds((const __attribute__((address_space(1))) unsigned int*)g,
                                   (__attribute__((address_space(3))) unsigned int*)l, 16, 0, 0);
}
static __device__ __forceinline__ float bf_lo(unsigned u) {
  return __builtin_bit_cast(float, u << 16);
}
static __device__ __forceinline__ float bf_hi(unsigned u) {
  return __builtin_bit_cast(float, u & 0xFFFF0000u);
}
static __device__ __forceinline__ float bfu(unsigned short u) {
  return __builtin_bit_cast(float, (unsigned)u << 16);
}
static __device__ __forceinline__ void wait_vm0_barrier() {
  asm volatile("s_waitcnt vmcnt(0)" ::: "memory");
  __builtin_amdgcn_s_barrier();
  __builtin_amdgcn_sched_barrier(0);
}

// ---------------- prep: x -> xn (bf16 x-hat, row-major) and xt (bf16 x^T, BLOCKED) ---------
// xt layout: [b][jt][d][j&31]  (jt = j>>5) -> each block owns ONE contiguous 32KB chunk.
// grid 512 = 8 batches (XCD-pinned &7) x 64 j-tiles of 32 rows ; 256 threads
__global__ __launch_bounds__(256) void prep_kernel(const float* __restrict__ x,
                                                   unsigned short* __restrict__ xn,
                                                   unsigned short* __restrict__ xt) {
  const int b   = blockIdx.x & 7;
  const int jt  = blockIdx.x >> 3;     // 0..63
  const int t   = threadIdx.x;
  const int row = t >> 3;              // 0..31
  const int oct = t & 7;               // 0..7

  __shared__ unsigned short xs[512 * 34];   // [d][j] bf16, pitch 34 u16 (34.8 KB)

  const long rowg = ((long)b * SEQ + jt * 32 + row) * DIM;
  const float* xp = x + rowg;

  float4 v[16];
#pragma unroll
  for (int k = 0; k < 16; ++k)
    v[k] = *reinterpret_cast<const float4*>(xp + k * 32 + oct * 4);

  float acc = 0.f;
#pragma unroll
  for (int k = 0; k < 16; ++k)
    acc += v[k].x*v[k].x + v[k].y*v[k].y + v[k].z*v[k].z + v[k].w*v[k].w;
  acc += __shfl_xor(acc, 1);
  acc += __shfl_xor(acc, 2);
  acc += __shfl_xor(acc, 4);
  const float sc = 1.f / (sqrtf(acc) + 1e-12f);

  // xn straight from registers
  unsigned short* xnp = xn + rowg + oct * 4;
#pragma unroll
  for (int k = 0; k < 16; ++k) {
    ushort4 pk;
    pk.x = f32_bf16(v[k].x * sc); pk.y = f32_bf16(v[k].y * sc);
    pk.z = f32_bf16(v[k].z * sc); pk.w = f32_bf16(v[k].w * sc);
    *reinterpret_cast<ushort4*>(xnp + k * 32) = pk;
  }

  // LDS transpose staging: scalar u16 writes, bank = 4*oct + row/2 + const -> free
#pragma unroll
  for (int k = 0; k < 16; ++k) {
    const int d = k * 32 + oct * 4;
    xs[(d + 0) * 34 + row] = f32_bf16(v[k].x);
    xs[(d + 1) * 34 + row] = f32_bf16(v[k].y);
    xs[(d + 2) * 34 + row] = f32_bf16(v[k].z);
    xs[(d + 3) * 34 + row] = f32_bf16(v[k].w);
  }
  __syncthreads();

  // xt chunk store: contiguous 32KB, fully coalesced.
  unsigned short* xtb = xt + (size_t)(b * 64 + jt) * (512 * 32);
#pragma unroll
  for (int it = 0; it < 8; ++it) {
    const int a = t >> 2;                      // 0..63 d-sub
    const int q = (t & 3) ^ ((t >> 4) & 3);    // read/store group 0..3
    const int d = it * 64 + a;
    const unsigned* bp = reinterpret_cast<const unsigned*>(&xs[d * 34 + q * 8]);
    uint4 o;
    o.x = bp[0]; o.y = bp[1]; o.z = bp[2]; o.w = bp[3];
    *reinterpret_cast<uint4*>(xtb + d * 32 + q * 8) = o;
  }
}

// ---------------- gemm1 (symmetric, T3-lite): P[b,i,j] = bf16(exp(S^2-1)) ----------
// Upper-triangle tiles (grid 8 x 136). 2-phase prefetch main loop: STAGE(kc+1) issued
// BEFORE compute(kc); raw s_barrier + asm vmcnt(0) once per kc (HIP __syncthreads would
// drain the prefetch). LDS 64KB dbuf (2 blk/CU), epilogue sP aliases buffers.
// Mirror tile now routed through LDS (2nd transposed sP pass) -> full-line stores.
__global__ __launch_bounds__(256, 2) void gemm1_kernel(const unsigned short* __restrict__ xn,
                                                       unsigned short* __restrict__ P,
                                                       float* __restrict__ lw) {
  const int b   = blockIdx.x & 7;
  int idx = blockIdx.x >> 3;           // 0..135 -> (ti, tj), ti <= tj
  int ti = 0;
#pragma unroll 1
  while (idx >= 16 - ti) { idx -= 16 - ti; ++ti; }
  const int tj = ti + idx;
  const int i0 = ti * 128;
  const int j0 = tj * 128;
  const bool diag = (ti == tj);

  const int tid  = threadIdx.x;
  const int w    = tid >> 6;
  const int lane = tid & 63;
  const int ln   = lane & 31;
  const int half = lane >> 5;

  // dbuf: buf k at k*16384 (A 8192 u16, B 8192 u16). sP (17408 u16) aliases buf0.
  __shared__ __align__(16) unsigned short smem[32768];   // 64 KB

  const unsigned short* xb = xn + (long)b * SEQ * DIM;
  const unsigned short* Ag = xb + (long)i0 * DIM;
  const unsigned short* Bg = xb + (long)j0 * DIM;

  floatx16 acc[2][2];
#pragma unroll
  for (int mt = 0; mt < 2; ++mt)
#pragma unroll
    for (int nt = 0; nt < 2; ++nt)
#pragma unroll
      for (int i = 0; i < 16; ++i) acc[mt][nt][i] = 0.f;

  const int r0 = (w >> 1) * 64;
  const int c0 = (w & 1) * 64;

  // ---- prologue: stage kc=0 into buf0 ----
  {
    unsigned short* bA = smem;
    unsigned short* bB = smem + 8192;
#pragma unroll
    for (int k = 0; k < 4; ++k) {
      int u = tid + k * 256;
      int row = u >> 3, c = u & 7;
      int gc = (c ^ ((row ^ (row >> 3)) & 7)) * 8;
      gld_lds16(Ag + (long)row * DIM + gc, bA + u * 8);
      if (!diag) gld_lds16(Bg + (long)row * DIM + gc, bB + u * 8);
    }
  }
  wait_vm0_barrier();

  for (int kc = 0; kc < 8; ++kc) {
    const int cur = kc & 1;
    if (kc < 7) {            // prefetch next chunk into the other buffer
      unsigned short* bA = smem + (cur ^ 1) * 16384;
      unsigned short* bB = bA + 8192;
      const int ko = (kc + 1) * 64;
#pragma unroll
      for (int k = 0; k < 4; ++k) {
        int u = tid + k * 256;
        int row = u >> 3, c = u & 7;
        int gc = (c ^ ((row ^ (row >> 3)) & 7)) * 8;
        gld_lds16(Ag + (long)row * DIM + ko + gc, bA + u * 8);
        if (!diag) gld_lds16(Bg + (long)row * DIM + ko + gc, bB + u * 8);
      }
      __builtin_amdgcn_sched_barrier(0);   // keep the issue cluster ahead of compute
    }
    unsigned short* cA = smem + cur * 16384;
    unsigned short* cB = diag ? cA : cA + 8192;
#pragma unroll
    for (int kk = 0; kk < 4; ++kk) {
      const int cc = kk * 2 + half;
      short8 af[2], bf[2];
#pragma unroll
      for (int mt = 0; mt < 2; ++mt) {
        int r = r0 + mt * 32 + ln;
        af[mt] = ld_frag8(cA + r * 64 + ((cc ^ ((r ^ (r >> 3)) & 7)) * 8));
      }
#pragma unroll
      for (int nt = 0; nt < 2; ++nt) {
        int r = c0 + nt * 32 + ln;
        bf[nt] = ld_frag8(cB + r * 64 + ((cc ^ ((r ^ (r >> 3)) & 7)) * 8));
      }
#pragma unroll
      for (int mt = 0; mt < 2; ++mt)
#pragma unroll
        for (int nt = 0; nt < 2; ++nt)
          acc[mt][nt] = __builtin_amdgcn_mfma_f32_32x32x16_bf16(af[mt], bf[nt], acc[mt][nt], 0, 0, 0);
    }
    wait_vm0_barrier();      // prefetch landed during compute; buffers safe to swap
  }

  // epilogue: p = bf16(exp(s^2-1)) once into registers; feed sP, mirror, sums
  unsigned short pb[2][2][16];
  unsigned short* sP = smem;
#pragma unroll
  for (int mt = 0; mt < 2; ++mt)
#pragma unroll
    for (int nt = 0; nt < 2; ++nt) {
      const int col = c0 + nt * 32 + ln;
#pragma unroll
      for (int r = 0; r < 16; ++r) {
        float s = acc[mt][nt][r];
        unsigned short pv = f32_bf16(__expf(__builtin_fmaf(s, s, -1.0f)));
        pb[mt][nt][r] = pv;
        int row = r0 + mt * 32 + (r & 3) + 8 * (r >> 2) + 4 * half;
        sP[row * 136 + col] = pv;
      }
    }
  __syncthreads();

  unsigned short* Pg = P + (long)b * SEQ * SEQ;
  float* lwi = lw + b * SEQ + i0;
  float* lwj = lw + b * SEQ + j0;

  // tile (ti,tj): coalesced stores + fused row-sums
#pragma unroll
  for (int k = 0; k < 8; ++k) {
    int u = tid + k * 256;
    int row = u >> 4, c16 = u & 15;
    uint4 o = *reinterpret_cast<const uint4*>(sP + row * 136 + c16 * 8);
    *reinterpret_cast<uint4*>(Pg + (long)(i0 + row) * SEQ + j0 + c16 * 8) = o;
    float s = bf_lo(o.x) + bf_hi(o.x) + bf_lo(o.y) + bf_hi(o.y)
            + bf_lo(o.z) + bf_hi(o.z) + bf_lo(o.w) + bf_hi(o.w);
    s += __shfl_xor(s, 1);
    s += __shfl_xor(s, 2);
    s += __shfl_xor(s, 4);
    s += __shfl_xor(s, 8);
    if ((tid & 15) == 0) atomicAdd(&lwi[row], s);
  }

  if (!diag) {
    // column sums (= row sums of the mirror tile) from the exact bf16 register values
#pragma unroll
    for (int nt = 0; nt < 2; ++nt) {
      const int c = c0 + nt * 32 + ln;
      float s = 0.f;
#pragma unroll
      for (int mt = 0; mt < 2; ++mt)
#pragma unroll
        for (int r = 0; r < 16; ++r) s += bfu(pb[mt][nt][r]);
      s += __shfl_xor(s, 32);           // combine the two row-halves of this wave
      if (half == 0) atomicAdd(&lwj[c], s);
    }
    __syncthreads();                    // direct-tile reads of sP complete
    // rewrite sP TRANSPOSED (sP[c][i]) from registers, then store coalesced full lines
#pragma unroll
    for (int nt = 0; nt < 2; ++nt) {
      const int c = c0 + nt * 32 + ln;
#pragma unroll
      for (int mt = 0; mt < 2; ++mt)
#pragma unroll
        for (int r = 0; r < 16; ++r) {
          const int row = r0 + mt * 32 + (r & 3) + 8 * (r >> 2) + 4 * half;
          sP[c * 136 + row] = pb[mt][nt][r];
        }
    }
    __syncthreads();
#pragma unroll
    for (int k = 0; k < 8; ++k) {
      int u = tid + k * 256;
      int row = u >> 4, c16 = u & 15;   // row = mirror row (j-col), c16 over i
      uint4 o = *reinterpret_cast<const uint4*>(sP + row * 136 + c16 * 8);
      *reinterpret_cast<uint4*>(Pg + (long)(j0 + row) * SEQ + i0 + c16 * 8) = o;
    }
  }
}

// ---------------- gemm2 (T3-lite): out[b,i,d] = (P . x) / l ----------------
// grid 512 = 8 batches x 16 i x 4 d ; 256 threads ; d-FAST ordering ; blocked-xt B staging.
// Same 2-phase prefetch loop; LDS 64KB dbuf -> 2 blk/CU.
__global__ __launch_bounds__(256, 2) void gemm2_kernel(const unsigned short* __restrict__ P,
                                                       const unsigned short* __restrict__ xt,
                                                       const float* __restrict__ lw,
                                                       float* __restrict__ out) {
  const int b  = blockIdx.x & 7;
  const int t  = blockIdx.x >> 3;
  const int i0 = (t >> 2) * 128;       // d-fast: i0 slow
  const int n0 = (t & 3) * 128;        // d-fast: n0 fast
  const int tid  = threadIdx.x;
  const int w    = tid >> 6;
  const int lane = tid & 63;
  const int ln   = lane & 31;
  const int half = lane >> 5;

  __shared__ __align__(16) unsigned short smem[32768];   // 64 KB dbuf
  __shared__ float sl[128];

  const unsigned short* Ag = P  + (long)b * SEQ * SEQ + (long)i0 * SEQ;
  const unsigned short* Bg = xt + (size_t)b * DIM * SEQ;   // blocked chunks base

  if (tid < 128) sl[tid] = lw[b * SEQ + i0 + tid];

  floatx16 acc[2][2];
#pragma unroll
  for (int mt = 0; mt < 2; ++mt)
#pragma unroll
    for (int nt = 0; nt < 2; ++nt)
#pragma unroll
      for (int i = 0; i < 16; ++i) acc[mt][nt][i] = 0.f;

  const int r0 = (w >> 1) * 64;
  const int c0 = (w & 1) * 64;

  // ---- prologue: stage kc=0 ----
  {
    unsigned short* bA = smem;
    unsigned short* bB = smem + 8192;
#pragma unroll
    for (int k = 0; k < 4; ++k) {
      int u = tid + k * 256;
      int row = u >> 3, c = u & 7;
      int sub = c ^ ((row ^ (row >> 3)) & 7);
      gld_lds16(Ag + (long)row * SEQ + sub * 8, bA + u * 8);
      gld_lds16(Bg + ((size_t)(sub >> 2) * 512 + (n0 + row)) * 32 + (sub & 3) * 8, bB + u * 8);
    }
  }
  wait_vm0_barrier();

  for (int kc = 0; kc < 32; ++kc) {
    const int cur = kc & 1;
    if (kc < 31) {
      unsigned short* bA = smem + (cur ^ 1) * 16384;
      unsigned short* bB = bA + 8192;
      const int kn = kc + 1;
#pragma unroll
      for (int k = 0; k < 4; ++k) {
        int u = tid + k * 256;
        int row = u >> 3, c = u & 7;
        int sub = c ^ ((row ^ (row >> 3)) & 7);
        gld_lds16(Ag + (long)row * SEQ + kn * 64 + sub * 8, bA + u * 8);
        gld_lds16(Bg + ((size_t)(kn * 2 + (sub >> 2)) * 512 + (n0 + row)) * 32 + (sub & 3) * 8,
                  bB + u * 8);
      }
      __builtin_amdgcn_sched_barrier(0);
    }
    unsigned short* cAb = smem + cur * 16384;
    unsigned short* cBb = cAb + 8192;
#pragma unroll
    for (int kk = 0; kk < 4; ++kk) {
      const int cc = kk * 2 + half;
      short8 af[2], bf[2];
#pragma unroll
      for (int mt = 0; mt < 2; ++mt) {
        int r = r0 + mt * 32 + ln;
        af[mt] = ld_frag8(cAb + r * 64 + ((cc ^ ((r ^ (r >> 3)) & 7)) * 8));
      }
#pragma unroll
      for (int nt = 0; nt < 2; ++nt) {
        int r = c0 + nt * 32 + ln;
        bf[nt] = ld_frag8(cBb + r * 64 + ((cc ^ ((r ^ (r >> 3)) & 7)) * 8));
      }
#pragma unroll
      for (int mt = 0; mt < 2; ++mt)
#pragma unroll
        for (int nt = 0; nt < 2; ++nt)
          acc[mt][nt] = __builtin_amdgcn_mfma_f32_32x32x16_bf16(af[mt], bf[nt], acc[mt][nt], 0, 0, 0);
    }
    wait_vm0_barrier();
  }

  // epilogue: divide by l, coalesced fp32 stores
  float* outb = out + (long)b * SEQ * DIM;
#pragma unroll
  for (int mt = 0; mt < 2; ++mt)
#pragma unroll
    for (int r = 0; r < 16; ++r) {
      const int row = r0 + mt * 32 + (r & 3) + 8 * (r >> 2) + 4 * half;
      const float inv = 1.0f / sl[row];
#pragma unroll
      for (int nt = 0; nt < 2; ++nt) {
        const int col = c0 + nt * 32 + ln;
        outb[(long)(i0 + row) * DIM + n0 + col] = acc[mt][nt][r] * inv;
      }
    }
}

extern "C" void kernel_launch(void* const* d_in, const int* in_sizes, int n_in,
                              void* d_out, int out_size, void* d_ws, size_t ws_size,
                              hipStream_t stream) {
  const float* x = (const float*)d_in[0];
  float* outp = (float*)d_out;

  unsigned short* xn = (unsigned short*)d_ws;                        // 16.78 MB
  unsigned short* xt = xn + (size_t)BATCH * SEQ * DIM;               // 16.78 MB (blocked)
  unsigned short* Pw = xt + (size_t)BATCH * SEQ * DIM;               // 67.1 MB
  float*          lw = (float*)(Pw + (size_t)BATCH * SEQ * SEQ);     // 64 KB

  hipMemsetAsync(lw, 0, (size_t)BATCH * SEQ * sizeof(float), stream);
  prep_kernel <<<BATCH * (SEQ / 32),  256, 0, stream>>>(x, xn, xt);
  gemm1_kernel<<<BATCH * 136,         256, 0, stream>>>(xn, Pw, lw);
  gemm2_kernel<<<BATCH * 16 * 4,      256, 0, stream>>>(Pw, xt, lw, outp);
}